// Round 6
// baseline (320.652 us; speedup 1.0000x reference)
//
#include <hip/hip_runtime.h>
#include <stdint.h>

// DomainAttentionLayer: out = softmax((x Wq^T + bq)(dx Wk^T + bk)^T / sqrt(D)) (dx Wv^T + bv)
// N = M = 8192, D = 512, fp32 in/out; internal compute bf16 MFMA.
//
// Pipeline:
//   0) prep_w    : W fp32 -> bf16 (once)
//   1) qkv_proj  : bf16 GEMMs, bias fused; Q pre-scaled by log2(e)/sqrt(D); V stored VT[D][M]
//   2) flash_attn: fused online-softmax attention, split-m x SPLITS partials.
//                  R8: ONE 512-thread block per CU (128 Q-rows, 8 waves) --
//                  removes duplicate K/VT DMA of 2 co-resident blocks; disjoint
//                  sK/sVT buffers -> VT(t) DMA hidden under S(t) MFMAs, K(t+1)
//                  DMA hidden under softmax(t); 3 barriers/iter, no exposed
//                  drains. DPP softmax + T13 defer-max + T5 setprio retained.
//   3) combine   : exact log-sum-exp merge of partials -> fp32 out

#define DEV __device__ __forceinline__

typedef short short8 __attribute__((ext_vector_type(8)));     // 8 bf16 (4 VGPRs) MFMA frag
typedef float floatx4 __attribute__((ext_vector_type(4)));    // MFMA accum
typedef unsigned int uintx4 __attribute__((ext_vector_type(4)));
typedef unsigned short ushortx4 __attribute__((ext_vector_type(4)));

constexpr int NN = 8192;
constexpr int MM = 8192;
constexpr int DD = 512;
constexpr float SCALE2 = 0.0637587160f;         // log2(e) / sqrt(512), folded into Q
constexpr float DEFER_THR = 6.0f;               // T13: P bounded by 2^6; exact math

#define NEG_INF (-__builtin_inff())

#if defined(__has_builtin)
#if __has_builtin(__builtin_amdgcn_exp2f)
#define EXP2F(x) __builtin_amdgcn_exp2f(x)
#else
#define EXP2F(x) exp2f(x)
#endif
#else
#define EXP2F(x) exp2f(x)
#endif

DEV unsigned short f2bf(float f) {              // RNE fp32 -> bf16 bits
  unsigned u = __builtin_bit_cast(unsigned, f);
  return (unsigned short)((u + 0x7FFFu + ((u >> 16) & 1u)) >> 16);
}
DEV float bf2f(unsigned short h) {
  unsigned u = ((unsigned)h) << 16;
  return __builtin_bit_cast(float, u);
}

// DPP rotate within 16-lane row (VALU pipe; row_ror:N = 0x120+N)
template <int CTRL>
DEV float dpp_rot(float x) {
  int xi = __builtin_bit_cast(int, x);
  return __builtin_bit_cast(float,
      __builtin_amdgcn_update_dpp(xi, xi, CTRL, 0xf, 0xf, false));
}
DEV float row_max16(float x) {   // max over the lane's 16-lane DPP row
  x = fmaxf(x, dpp_rot<0x121>(x));   // ror:1
  x = fmaxf(x, dpp_rot<0x122>(x));   // ror:2
  x = fmaxf(x, dpp_rot<0x124>(x));   // ror:4
  x = fmaxf(x, dpp_rot<0x128>(x));   // ror:8
  return x;
}
DEV float row_sum16(float x) {   // sum over the lane's 16-lane DPP row
  x += dpp_rot<0x121>(x);
  x += dpp_rot<0x122>(x);
  x += dpp_rot<0x124>(x);
  x += dpp_rot<0x128>(x);
  return x;
}

// TBAA-safe vector ld/st (memcpy compiles to single b128/b64 with assumed alignment)
DEV short8 ld_s8(const void* p) {
  short8 v; __builtin_memcpy(&v, __builtin_assume_aligned(p, 16), 16); return v;
}
DEV uintx4 ld_u4(const void* p) {
  uintx4 v; __builtin_memcpy(&v, __builtin_assume_aligned(p, 16), 16); return v;
}
DEV void st_u4(void* p, uintx4 v) {
  __builtin_memcpy(__builtin_assume_aligned(p, 16), &v, 16);
}
DEV void st_us4(void* p, ushortx4 v) {
  __builtin_memcpy(__builtin_assume_aligned(p, 8), &v, 8);
}
DEV float4 ld_f4(const void* p) {
  float4 v; __builtin_memcpy(&v, __builtin_assume_aligned(p, 16), 16); return v;
}

DEV void async_lds16(const void* g, const void* l) {  // global -> LDS DMA, 16B/lane
  __builtin_amdgcn_global_load_lds(
      (const __attribute__((address_space(1))) unsigned int*)g,
      (__attribute__((address_space(3))) unsigned int*)l, 16, 0, 0);
}

// ---------------------------------------------------------------------------
// Kernel 0: W fp32 -> bf16, once. grid (128, 1, 3), block 256, 8 elems/thread.
// ---------------------------------------------------------------------------
__global__ void prep_w(const float* __restrict__ Wq, const float* __restrict__ Wk,
                       const float* __restrict__ Wv, unsigned short* __restrict__ Wb) {
  const int z = blockIdx.z;
  const float* src = (z == 0) ? Wq : (z == 1) ? Wk : Wv;
  unsigned short* dst = Wb + (size_t)z * DD * DD;
  size_t idx = ((size_t)blockIdx.x * 256 + threadIdx.x) * 8;
  float4 a = ld_f4(src + idx);
  float4 b = ld_f4(src + idx + 4);
  ushortx4 lo = {f2bf(a.x), f2bf(a.y), f2bf(a.z), f2bf(a.w)};
  ushortx4 hi = {f2bf(b.x), f2bf(b.y), f2bf(b.z), f2bf(b.w)};
  st_us4(dst + idx, lo);
  st_us4(dst + idx + 4, hi);
}

// ---------------------------------------------------------------------------
// Kernel 1: QKV projection. grid (128, 2, 3), block 256. Tile 64 rows x 256 cols,
// BK=64. LDS xor-swizzled (chunk ^= row&7) -> conflict-free b128 frag reads.
// z=0: Q (scaled by SCALE2) -> Qb[N][D]; z=1: K -> Kb[M][D]; z=2: V -> VTb[D][M].
// ---------------------------------------------------------------------------
__global__ __launch_bounds__(256, 2)
void qkv_proj(const float* __restrict__ x, const float* __restrict__ dx,
              const unsigned short* __restrict__ Wb,
              const float* __restrict__ bq, const float* __restrict__ bk,
              const float* __restrict__ bv,
              unsigned short* __restrict__ Qb, unsigned short* __restrict__ Kb,
              unsigned short* __restrict__ VTb) {
  const int z = blockIdx.z;
  const float* A = (z == 0) ? x : dx;
  const unsigned short* W = Wb + (size_t)z * DD * DD;
  const float* bias = (z == 0) ? bq : (z == 1) ? bk : bv;

  const int r0 = blockIdx.x * 64;
  const int c0 = blockIdx.y * 256;
  const int tid = threadIdx.x;
  const int lane = tid & 63;
  const int wave = tid >> 6;
  const int lr = lane & 15;
  const int quad = lane >> 4;

  __shared__ __align__(16) unsigned short As[64 * 64];   //  8 KB
  __shared__ __align__(16) unsigned short Ws[256 * 64];  // 32 KB

  floatx4 o[16];
#pragma unroll
  for (int i = 0; i < 16; ++i) o[i] = {0.f, 0.f, 0.f, 0.f};

  for (int k0 = 0; k0 < DD; k0 += 64) {
    // stage A tile (fp32 -> bf16): 64 rows x 64 k, 4 float4 per thread
#pragma unroll
    for (int i = 0; i < 4; ++i) {
      int idx = i * 256 + tid;
      int r = idx >> 4, c4 = idx & 15;
      float4 v = ld_f4(A + (size_t)(r0 + r) * DD + k0 + c4 * 4);
      ushortx4 pk = {f2bf(v.x), f2bf(v.y), f2bf(v.z), f2bf(v.w)};
      st_us4(&As[r * 64 + (((c4 >> 1) ^ (r & 7)) * 8) + (c4 & 1) * 4], pk);
    }
    // stage W tile (bf16, no convert): 256 rows x 64 k, 8 x 16B per thread
#pragma unroll
    for (int i = 0; i < 8; ++i) {
      int idx = i * 256 + tid;
      int r = idx >> 3, c = idx & 7;
      uintx4 v = ld_u4(W + (size_t)(c0 + r) * DD + k0 + c * 8);
      st_u4(&Ws[r * 64 + ((c ^ (r & 7)) * 8)], v);
    }
    __syncthreads();

    short8 a[2];
#pragma unroll
    for (int ks = 0; ks < 2; ++ks)
      a[ks] = ld_s8(&As[(wave * 16 + lr) * 64 + (((ks * 4 + quad) ^ (lr & 7)) * 8)]);
#pragma unroll
    for (int ct = 0; ct < 16; ++ct) {
#pragma unroll
      for (int ks = 0; ks < 2; ++ks) {
        short8 b = ld_s8(&Ws[(ct * 16 + lr) * 64 + (((ks * 4 + quad) ^ (lr & 7)) * 8)]);
        o[ct] = __builtin_amdgcn_mfma_f32_16x16x32_bf16(a[ks], b, o[ct], 0, 0, 0);
      }
    }
    __syncthreads();
  }

  // epilogue: bias (+Q scale), store. C layout: col = lr, row = quad*4 + reg.
#pragma unroll
  for (int ct = 0; ct < 16; ++ct) {
    int col = c0 + ct * 16 + lr;
    float bv_ = bias[col];
    int rowb = r0 + wave * 16 + quad * 4;
    if (z == 2) {  // VT[col][row], 4 consecutive rows -> 8B store
      ushortx4 pk = {f2bf(o[ct][0] + bv_), f2bf(o[ct][1] + bv_),
                     f2bf(o[ct][2] + bv_), f2bf(o[ct][3] + bv_)};
      st_us4(VTb + (size_t)col * MM + rowb, pk);
    } else {
      unsigned short* Outp = (z == 0) ? Qb : Kb;
      float sc = (z == 0) ? SCALE2 : 1.f;
#pragma unroll
      for (int r = 0; r < 4; ++r)
        Outp[(size_t)(rowb + r) * DD + col] = f2bf((o[ct][r] + bv_) * sc);
    }
  }
}

// ---------------------------------------------------------------------------
// Kernel 2: flash attention. 1-D grid (N/128 * SPLITS_) = 256 blocks, block 512
// (8 waves), 1 block/CU (LDS ~149 KB). Q tile 128 rows.
// S phase: wave w owns q-rows [16w,16w+16) (identical structure to before).
// PV phase: wave w = (wrow = w&1, wcol = w>>1) computes
//   O[rows wrow*64 .. +64)[cols wcol*128 .. +128) -- same o[32]/pa[4] shape.
// Disjoint buffers: sK (64x520), sVT (512x64, chunk^row&7 swizzle via DMA src),
// sP (128x64, chunk-XOR swizzle).
// Schedule/iter: [issue VT(t) | S(t)] B1 [issue K(t+1) | softmax | P] B2
//                [rescale? | PV(t)] B3 -- both DMA streams fully hidden.
// ---------------------------------------------------------------------------
template <int SPLITS_, int LOG2S_>
__global__ __launch_bounds__(512, 2)
void flash_attn(const unsigned short* __restrict__ Qb,
                const unsigned short* __restrict__ Kb,
                const unsigned short* __restrict__ VTb,
                unsigned short* __restrict__ Opart,
                float* __restrict__ Mpart, float* __restrict__ Lpart) {
  constexpr int MT = MM / SPLITS_;
  constexpr int ITERS = MT / 64;
  const int lin = blockIdx.x;
  const int split = lin & (SPLITS_ - 1);
  const int n0 = (lin >> LOG2S_) * 128;
  const int m_begin = split * MT;

  const int tid = threadIdx.x;
  const int lane = tid & 63;
  const int wave = tid >> 6;        // 0..7
  const int lr = lane & 15;
  const int quad = lane >> 4;
  const int wrow = wave & 1;        // PV row-half
  const int wcol = wave >> 1;       // PV col-quarter (128 d-cols)

  __shared__ __align__(16) unsigned short sK[64 * 520];    // 66,560 B
  __shared__ __align__(16) unsigned short sVT[512 * 64];   // 65,536 B
  __shared__ __align__(16) unsigned short sP[128 * 64];    // 16,384 B
  __shared__ float sAlpha[128];                            //    512 B
  __shared__ int sNeed;                                    // rescale flag

  if (tid == 0) sNeed = 0;  // ordered before first read by prologue barrier + B2

  // resident Q fragments: wave's 16 rows x 512 k (64 VGPRs), pre-scaled by SCALE2
  short8 qf[16];
  {
    const unsigned short* qptr = Qb + (size_t)(n0 + wave * 16 + lr) * DD + quad * 8;
#pragma unroll
    for (int ks = 0; ks < 16; ++ks) qf[ks] = ld_s8(qptr + ks * 32);
  }

  // VT DMA per-lane source geometry (swizzle in source, dest lane-contiguous):
  // wave stages VT d-rows [wave*64, wave*64+64). Group j covers rows 8j..8j+7.
  // lane i: LDS row r = 8j + (i>>3), chunk c' = i&7; source chunk c = c' ^ (r&7).
  const int vrb = lane >> 3;                                   // 0..7
  const int vcb = ((lane & 7) ^ vrb) * 8;                      // r&7 == vrb
  const unsigned short* vsrc0 = VTb + (size_t)(wave * 64 + vrb) * MM + vcb;
  unsigned short* vdst0 = &sVT[wave * 64 * 64];

  floatx4 o[32];  // [rt*8+ct]: O rows wrow*64+rt*16+quad*4+reg, col wcol*128+ct*16+lr
#pragma unroll
  for (int i = 0; i < 32; ++i) o[i] = {0.f, 0.f, 0.f, 0.f};
  float mrow[4] = {NEG_INF, NEG_INF, NEG_INF, NEG_INF};
  float lrow[4] = {0.f, 0.f, 0.f, 0.f};

  // ---- prologue: stage K(0); rows wave*8..wave*8+8, one 1024B DMA per row
#pragma unroll
  for (int i = 0; i < 8; ++i) {
    const int r = wave * 8 + i;  // wave-uniform LDS dest
    async_lds16(Kb + (size_t)(m_begin + r) * DD + lane * 8, &sK[r * 520]);
  }
  __syncthreads();  // drains K(0)

  for (int it = 0; it < ITERS; ++it) {
    const int m0 = m_begin + it * 64;

    // ---- issue VT(t) DMA (VT region free since B3 of prev iter); latency
    // hidden under the S-phase MFMAs below.
    {
      const unsigned short* src = vsrc0 + m0;
#pragma unroll
      for (int j = 0; j < 8; ++j)
        async_lds16(src + (size_t)j * 8 * MM, vdst0 + j * 512);
    }

    // ---- S = Q K^T (wave: its 16 rows x 64 cols), logits already in log2 units
    floatx4 s[4];
#pragma unroll
    for (int ct = 0; ct < 4; ++ct) s[ct] = {0.f, 0.f, 0.f, 0.f};
    __builtin_amdgcn_s_setprio(1);
#pragma unroll
    for (int ks = 0; ks < 16; ++ks) {
      const unsigned short* kb = &sK[ks * 32 + quad * 8];
#pragma unroll
      for (int ct = 0; ct < 4; ++ct) {
        short8 b = ld_s8(kb + (ct * 16 + lr) * 520);
        s[ct] = __builtin_amdgcn_mfma_f32_16x16x32_bf16(qf[ks], b, s[ct], 0, 0, 0);
      }
    }
    __builtin_amdgcn_s_setprio(0);
    __syncthreads();  // (B1) S done reading sK; VT(t) drained -> ready for PV

    // ---- prefetch K(t+1); latency hidden under softmax, drained at B2
    if (it + 1 < ITERS) {
#pragma unroll
      for (int i = 0; i < 8; ++i) {
        const int r = wave * 8 + i;
        async_lds16(Kb + (size_t)(m0 + 64 + r) * DD + lane * 8, &sK[r * 520]);
      }
    }

    // ---- online softmax with deferred max (T13), DPP rotate-reduce (VALU).
    float alpha[4];
    bool anyresc = false;
#pragma unroll
    for (int r = 0; r < 4; ++r) {
      float mx = fmaxf(fmaxf(s[0][r], s[1][r]), fmaxf(s[2][r], s[3][r]));
      mx = row_max16(mx);
      float mnew = (mx > mrow[r] + DEFER_THR) ? mx : mrow[r];  // -inf: always take
      alpha[r] = EXP2F(mrow[r] - mnew);  // 1 when deferred; 0 on first iter
      anyresc = anyresc || (mnew != mrow[r]);
      mrow[r] = mnew;
      float rs = 0.f;
#pragma unroll
      for (int ct = 0; ct < 4; ++ct) {
        float p = EXP2F(s[ct][r] - mnew);   // bounded by 2^THR
        s[ct][r] = p;
        rs += p;
      }
      rs = row_sum16(rs);
      lrow[r] = lrow[r] * alpha[r] + rs;
    }
    if (__any(anyresc)) {
      if (lane == 0) sNeed = 1;   // benign multi-wave race: all write 1
    }
    if (lr == 0) {
#pragma unroll
      for (int r = 0; r < 4; ++r) sAlpha[wave * 16 + quad * 4 + r] = alpha[r];
    }

    // ---- P (C layout) -> shared LDS bf16, stride 64 us, chunk-XOR swizzle.
#pragma unroll
    for (int ct = 0; ct < 4; ++ct)
#pragma unroll
      for (int r = 0; r < 4; ++r)
        sP[(wave * 16 + quad * 4 + r) * 64 +
           (((2 * ct + (lr >> 3)) ^ (2 * quad)) * 8) + (lr & 7)] = f2bf(s[ct][r]);

    __syncthreads();  // (B2) drains K(t+1); P + alphas + flag visible

    // ---- rescale O by this wave's PV-row-half alphas -- rarely taken
    if (sNeed) {      // block-uniform branch; ~never taken after iter 0
#pragma unroll
      for (int rt = 0; rt < 4; ++rt) {
        float4 t = ld_f4(&sAlpha[wrow * 64 + rt * 16 + quad * 4]);
#pragma unroll
        for (int ct = 0; ct < 8; ++ct) {
          o[rt * 8 + ct][0] *= t.x;
          o[rt * 8 + ct][1] *= t.y;
          o[rt * 8 + ct][2] *= t.z;
          o[rt * 8 + ct][3] *= t.w;
        }
      }
    }

    // ---- O += P V: A = P rows (wave's 64-row half), B = VT (wave's 128 d-cols)
    __builtin_amdgcn_s_setprio(1);
#pragma unroll
    for (int ks = 0; ks < 2; ++ks) {
      short8 pa[4];
#pragma unroll
      for (int rt = 0; rt < 4; ++rt)
        pa[rt] = ld_s8(&sP[(wrow * 64 + rt * 16 + lr) * 64 +
                           (((4 * ks + quad) ^ (2 * ((lr >> 2) & 3))) * 8)]);
#pragma unroll
      for (int ct = 0; ct < 8; ++ct) {
        const int r = wcol * 128 + ct * 16 + lr;  // sVT row = d-col; r&7 == lr&7
        short8 b = ld_s8(&sVT[r * 64 + (((ks * 4 + quad) ^ (lr & 7)) * 8)]);
#pragma unroll
        for (int rt = 0; rt < 4; ++rt)
          o[rt * 8 + ct] = __builtin_amdgcn_mfma_f32_16x16x32_bf16(pa[rt], b,
                                                                   o[rt * 8 + ct], 0, 0, 0);
      }
    }
    __builtin_amdgcn_s_setprio(0);
    __syncthreads();  // (B3) sVT/sP free for next iter's DMA / writes
    if (tid == 0) sNeed = 0;  // after B3 (readers done), before next B1 (setters)
  }

  // ---- epilogue: unnormalized partials (PV layout)
  unsigned short* op = Opart + (size_t)split * NN * DD;
#pragma unroll
  for (int rt = 0; rt < 4; ++rt)
#pragma unroll
    for (int ct = 0; ct < 8; ++ct) {
      int row = n0 + wrow * 64 + rt * 16 + quad * 4;
      int col = wcol * 128 + ct * 16 + lr;
#pragma unroll
      for (int r = 0; r < 4; ++r)
        op[(size_t)(row + r) * DD + col] = f2bf(o[rt * 8 + ct][r]);
    }
  const int grow = n0 + wave * 16 + quad * 4;
  if (lr == 0) {
#pragma unroll
    for (int r = 0; r < 4; ++r) {
      Mpart[split * NN + grow + r] = mrow[r];
      Lpart[split * NN + grow + r] = lrow[r];
    }
  }
}

// ---------------------------------------------------------------------------
// Kernel 3: exact softmax merge of SPLITS partials. 8 elems/thread, b128 I/O.
// grid (N*D/2048), block 256.
// ---------------------------------------------------------------------------
template <int SPLITS_>
__global__ void combine_kernel(const unsigned short* __restrict__ Op,
                               const float* __restrict__ Mp,
                               const float* __restrict__ Lp,
                               float* __restrict__ out) {
  constexpr size_t NDv = (size_t)NN * DD;
  size_t base = ((size_t)blockIdx.x * 256 + threadIdx.x) * 8;
  int n = (int)(base >> 9);
  float mv[SPLITS_];
  float ms = NEG_INF;
#pragma unroll
  for (int s = 0; s < SPLITS_; ++s) {
    mv[s] = Mp[s * NN + n];
    ms = fmaxf(ms, mv[s]);
  }
  float num[8];
#pragma unroll
  for (int j = 0; j < 8; ++j) num[j] = 0.f;
  float den = 0.f;
#pragma unroll
  for (int s = 0; s < SPLITS_; ++s) {
    float w = EXP2F(mv[s] - ms);
    den += w * Lp[s * NN + n];
    uintx4 u = ld_u4(Op + s * NDv + base);
#pragma unroll
    for (int j = 0; j < 4; ++j) {
      num[2 * j]     += w * bf2f((unsigned short)(u[j] & 0xffffu));
      num[2 * j + 1] += w * bf2f((unsigned short)(u[j] >> 16));
    }
  }
  float inv = 1.f / den;
  float4 o0 = {num[0] * inv, num[1] * inv, num[2] * inv, num[3] * inv};
  float4 o1 = {num[4] * inv, num[5] * inv, num[6] * inv, num[7] * inv};
  __builtin_memcpy(__builtin_assume_aligned(out + base, 16), &o0, 16);
  __builtin_memcpy(__builtin_assume_aligned(out + base + 4, 16), &o1, 16);
}

// ---------------------------------------------------------------------------
extern "C" void kernel_launch(void* const* d_in, const int* in_sizes, int n_in,
                              void* d_out, int out_size, void* d_ws, size_t ws_size,
                              hipStream_t stream) {
  const float* x  = (const float*)d_in[0];
  const float* dx = (const float*)d_in[1];
  const float* Wq = (const float*)d_in[2];
  const float* bq = (const float*)d_in[3];
  const float* Wk = (const float*)d_in[4];
  const float* bk = (const float*)d_in[5];
  const float* Wv = (const float*)d_in[6];
  const float* bv = (const float*)d_in[7];
  float* out = (float*)d_out;

  const size_t ND = (size_t)NN * DD;          // 4,194,304
  const size_t WBE = (size_t)3 * DD * DD;     //   786,432
  unsigned short* Qb  = (unsigned short*)d_ws;     // bf16, ND (pre-scaled)
  unsigned short* Kb  = Qb + ND;                   // bf16, ND
  unsigned short* VTb = Kb + ND;                   // bf16, ND (transposed V)
  unsigned short* Wb  = VTb + ND;                  // bf16, 3*D*D
  unsigned short* Op  = Wb + WBE;                  // bf16, splits*ND partial O

  auto bytes_for = [&](size_t S) {
    return (3 * ND + WBE + S * ND) * 2 + S * (size_t)NN * 8;
  };
  const int splits = (ws_size >= bytes_for(4)) ? 4 : 2;  // ws_size fixed -> same every call
  float* Mp = (float*)(Op + (size_t)splits * ND);
  float* Lp = Mp + (size_t)splits * NN;

  hipLaunchKernelGGL(prep_w, dim3(DD * DD / 2048, 1, 3), dim3(256), 0, stream,
                     Wq, Wk, Wv, Wb);
  hipLaunchKernelGGL(qkv_proj, dim3(NN / 64, 2, 3), dim3(256), 0, stream,
                     x, dx, Wb, bq, bk, bv, Qb, Kb, VTb);
  if (splits == 4) {
    hipLaunchKernelGGL((flash_attn<4, 2>), dim3(NN / 128 * 4), dim3(512), 0, stream,
                       Qb, Kb, VTb, Op, Mp, Lp);
    hipLaunchKernelGGL(combine_kernel<4>, dim3((unsigned)(ND / 2048)), dim3(256), 0, stream,
                       Op, Mp, Lp, out);
  } else {
    hipLaunchKernelGGL((flash_attn<2, 1>), dim3(NN / 128 * 2), dim3(512), 0, stream,
                       Qb, Kb, VTb, Op, Mp, Lp);
    hipLaunchKernelGGL(combine_kernel<2>, dim3((unsigned)(ND / 2048)), dim3(256), 0, stream,
                       Op, Mp, Lp, out);
  }
}

// Round 7
// 302.487 us; speedup vs baseline: 1.0601x; 1.0601x over previous
//
#include <hip/hip_runtime.h>
#include <stdint.h>

// DomainAttentionLayer: out = softmax((x Wq^T + bq)(dx Wk^T + bk)^T / sqrt(D)) (dx Wv^T + bv)
// N = M = 8192, D = 512, fp32 in/out; internal compute bf16 MFMA.
//
// Pipeline:
//   0) prep_w    : W fp32 -> bf16 (once)
//   1) qkv_proj  : bf16 GEMMs, bias fused; R9: W tile staged via global_load_lds
//                  DMA (xor-swizzle folded into per-lane source addrs), hidden
//                  under the manual A-stage fp32->bf16 convert.
//   2) flash_attn: R7 verified version (205.6 us): 256-thread blocks, 2/CU --
//                  inter-block phase diversity beats single-block lockstep (R8).
//                  DPP softmax, T13 defer-max, T5 setprio, chunk-XOR sP.
//   3) combine   : exact log-sum-exp merge of partials -> fp32 out
//
// Notes from profiling: SQ_LDS_BANK_CONFLICT ~1.9e7 is invariant across all
// layouts -- inherent wave64 b128 multi-cycle serialization, not fixable.

#define DEV __device__ __forceinline__

typedef short short8 __attribute__((ext_vector_type(8)));     // 8 bf16 (4 VGPRs) MFMA frag
typedef float floatx4 __attribute__((ext_vector_type(4)));    // MFMA accum
typedef unsigned int uintx4 __attribute__((ext_vector_type(4)));
typedef unsigned short ushortx4 __attribute__((ext_vector_type(4)));

constexpr int NN = 8192;
constexpr int MM = 8192;
constexpr int DD = 512;
constexpr float SCALE2 = 0.0637587160f;         // log2(e) / sqrt(512), folded into Q
constexpr float DEFER_THR = 6.0f;               // T13: P bounded by 2^6; exact math

#define NEG_INF (-__builtin_inff())

#if defined(__has_builtin)
#if __has_builtin(__builtin_amdgcn_exp2f)
#define EXP2F(x) __builtin_amdgcn_exp2f(x)
#else
#define EXP2F(x) exp2f(x)
#endif
#else
#define EXP2F(x) exp2f(x)
#endif

DEV unsigned short f2bf(float f) {              // RNE fp32 -> bf16 bits
  unsigned u = __builtin_bit_cast(unsigned, f);
  return (unsigned short)((u + 0x7FFFu + ((u >> 16) & 1u)) >> 16);
}
DEV float bf2f(unsigned short h) {
  unsigned u = ((unsigned)h) << 16;
  return __builtin_bit_cast(float, u);
}

// DPP rotate within 16-lane row (VALU pipe; row_ror:N = 0x120+N)
template <int CTRL>
DEV float dpp_rot(float x) {
  int xi = __builtin_bit_cast(int, x);
  return __builtin_bit_cast(float,
      __builtin_amdgcn_update_dpp(xi, xi, CTRL, 0xf, 0xf, false));
}
DEV float row_max16(float x) {   // max over the lane's 16-lane DPP row
  x = fmaxf(x, dpp_rot<0x121>(x));   // ror:1
  x = fmaxf(x, dpp_rot<0x122>(x));   // ror:2
  x = fmaxf(x, dpp_rot<0x124>(x));   // ror:4
  x = fmaxf(x, dpp_rot<0x128>(x));   // ror:8
  return x;
}
DEV float row_sum16(float x) {   // sum over the lane's 16-lane DPP row
  x += dpp_rot<0x121>(x);
  x += dpp_rot<0x122>(x);
  x += dpp_rot<0x124>(x);
  x += dpp_rot<0x128>(x);
  return x;
}

// TBAA-safe vector ld/st (memcpy compiles to single b128/b64 with assumed alignment)
DEV short8 ld_s8(const void* p) {
  short8 v; __builtin_memcpy(&v, __builtin_assume_aligned(p, 16), 16); return v;
}
DEV uintx4 ld_u4(const void* p) {
  uintx4 v; __builtin_memcpy(&v, __builtin_assume_aligned(p, 16), 16); return v;
}
DEV void st_u4(void* p, uintx4 v) {
  __builtin_memcpy(__builtin_assume_aligned(p, 16), &v, 16);
}
DEV void st_us4(void* p, ushortx4 v) {
  __builtin_memcpy(__builtin_assume_aligned(p, 8), &v, 8);
}
DEV float4 ld_f4(const void* p) {
  float4 v; __builtin_memcpy(&v, __builtin_assume_aligned(p, 16), 16); return v;
}

DEV void async_lds16(const void* g, const void* l) {  // global -> LDS DMA, 16B/lane
  __builtin_amdgcn_global_load_lds(
      (const __attribute__((address_space(1))) unsigned int*)g,
      (__attribute__((address_space(3))) unsigned int*)l, 16, 0, 0);
}

// ---------------------------------------------------------------------------
// Kernel 0: W fp32 -> bf16, once. grid (128, 1, 3), block 256, 8 elems/thread.
// ---------------------------------------------------------------------------
__global__ void prep_w(const float* __restrict__ Wq, const float* __restrict__ Wk,
                       const float* __restrict__ Wv, unsigned short* __restrict__ Wb) {
  const int z = blockIdx.z;
  const float* src = (z == 0) ? Wq : (z == 1) ? Wk : Wv;
  unsigned short* dst = Wb + (size_t)z * DD * DD;
  size_t idx = ((size_t)blockIdx.x * 256 + threadIdx.x) * 8;
  float4 a = ld_f4(src + idx);
  float4 b = ld_f4(src + idx + 4);
  ushortx4 lo = {f2bf(a.x), f2bf(a.y), f2bf(a.z), f2bf(a.w)};
  ushortx4 hi = {f2bf(b.x), f2bf(b.y), f2bf(b.z), f2bf(b.w)};
  st_us4(dst + idx, lo);
  st_us4(dst + idx + 4, hi);
}

// ---------------------------------------------------------------------------
// Kernel 1: QKV projection. grid (128, 2, 3), block 256. Tile 64 rows x 256 cols,
// BK=64. R9: W tile staged by global_load_lds DMA -- swizzle (chunk ^= row&7)
// folded into per-lane SOURCE addresses, dest lane-contiguous (group = 8 rows
// = 1024B = one wave DMA). Issued before the manual A-stage so the DMA latency
// hides under the fp32->bf16 convert. A tile stays manual (needs convert).
// z=0: Q (scaled by SCALE2) -> Qb[N][D]; z=1: K -> Kb[M][D]; z=2: V -> VTb[D][M].
// ---------------------------------------------------------------------------
__global__ __launch_bounds__(256, 2)
void qkv_proj(const float* __restrict__ x, const float* __restrict__ dx,
              const unsigned short* __restrict__ Wb,
              const float* __restrict__ bq, const float* __restrict__ bk,
              const float* __restrict__ bv,
              unsigned short* __restrict__ Qb, unsigned short* __restrict__ Kb,
              unsigned short* __restrict__ VTb) {
  const int z = blockIdx.z;
  const float* A = (z == 0) ? x : dx;
  const unsigned short* W = Wb + (size_t)z * DD * DD;
  const float* bias = (z == 0) ? bq : (z == 1) ? bk : bv;

  const int r0 = blockIdx.x * 64;
  const int c0 = blockIdx.y * 256;
  const int tid = threadIdx.x;
  const int lane = tid & 63;
  const int wave = tid >> 6;
  const int lr = lane & 15;
  const int quad = lane >> 4;

  __shared__ __align__(16) unsigned short As[64 * 64];   //  8 KB
  __shared__ __align__(16) unsigned short Ws[256 * 64];  // 32 KB

  // W DMA per-lane source geometry (same pattern as flash VT staging):
  // group g covers W rows 8g..8g+7 -> Ws us [g*512, g*512+512).
  // lane i: row r = 8g+(i>>3), dest chunk c' = i&7, source chunk c = c'^(r&7).
  const int vrb = lane >> 3;                       // 0..7
  const int vcb = ((lane & 7) ^ vrb) * 8;          // us offset of source chunk

  floatx4 o[16];
#pragma unroll
  for (int i = 0; i < 16; ++i) o[i] = {0.f, 0.f, 0.f, 0.f};

  for (int k0 = 0; k0 < DD; k0 += 64) {
    // issue W tile DMA: 32 groups of 8 rows; wave w takes groups w*8..w*8+7
#pragma unroll
    for (int j = 0; j < 8; ++j) {
      const int g = wave * 8 + j;
      async_lds16(W + (size_t)(c0 + g * 8 + vrb) * DD + k0 + vcb, &Ws[g * 512]);
    }
    // stage A tile (fp32 -> bf16): 64 rows x 64 k, 4 float4 per thread
#pragma unroll
    for (int i = 0; i < 4; ++i) {
      int idx = i * 256 + tid;
      int r = idx >> 4, c4 = idx & 15;
      float4 v = ld_f4(A + (size_t)(r0 + r) * DD + k0 + c4 * 4);
      ushortx4 pk = {f2bf(v.x), f2bf(v.y), f2bf(v.z), f2bf(v.w)};
      st_us4(&As[r * 64 + (((c4 >> 1) ^ (r & 7)) * 8) + (c4 & 1) * 4], pk);
    }
    __syncthreads();  // drains W DMA (vmcnt) + A writes

    short8 a[2];
#pragma unroll
    for (int ks = 0; ks < 2; ++ks)
      a[ks] = ld_s8(&As[(wave * 16 + lr) * 64 + (((ks * 4 + quad) ^ (lr & 7)) * 8)]);
#pragma unroll
    for (int ct = 0; ct < 16; ++ct) {
#pragma unroll
      for (int ks = 0; ks < 2; ++ks) {
        short8 b = ld_s8(&Ws[(ct * 16 + lr) * 64 + (((ks * 4 + quad) ^ (lr & 7)) * 8)]);
        o[ct] = __builtin_amdgcn_mfma_f32_16x16x32_bf16(a[ks], b, o[ct], 0, 0, 0);
      }
    }
    __syncthreads();
  }

  // epilogue: bias (+Q scale), store. C layout: col = lr, row = quad*4 + reg.
#pragma unroll
  for (int ct = 0; ct < 16; ++ct) {
    int col = c0 + ct * 16 + lr;
    float bv_ = bias[col];
    int rowb = r0 + wave * 16 + quad * 4;
    if (z == 2) {  // VT[col][row], 4 consecutive rows -> 8B store
      ushortx4 pk = {f2bf(o[ct][0] + bv_), f2bf(o[ct][1] + bv_),
                     f2bf(o[ct][2] + bv_), f2bf(o[ct][3] + bv_)};
      st_us4(VTb + (size_t)col * MM + rowb, pk);
    } else {
      unsigned short* Outp = (z == 0) ? Qb : Kb;
      float sc = (z == 0) ? SCALE2 : 1.f;
#pragma unroll
      for (int r = 0; r < 4; ++r)
        Outp[(size_t)(rowb + r) * DD + col] = f2bf((o[ct][r] + bv_) * sc);
    }
  }
}

// ---------------------------------------------------------------------------
// Kernel 2: flash attention (R7 verified, 205.6 us). 1-D grid (N/64 * SPLITS_),
// block 256, 2 blocks/CU. S phase: wave w owns q-rows [16w,16w+16). PV phase
// (D-split): wave w computes O[all 64 rows][cols 128w..128w+128); P (64x64) +
// alphas shared via LDS. T13 defer-max; T5 setprio; DPP rotate-reduce softmax.
// sP: stride 64 us, 16B-chunk swizzled: chunk' = chunk ^ (2*((row>>2)&3)).
// LDS 75,016 B -> 2 blocks/CU, no spill.
// ---------------------------------------------------------------------------
template <int SPLITS_, int LOG2S_>
__global__ __launch_bounds__(256, 2)
void flash_attn(const unsigned short* __restrict__ Qb,
                const unsigned short* __restrict__ Kb,
                const unsigned short* __restrict__ VTb,
                unsigned short* __restrict__ Opart,
                float* __restrict__ Mpart, float* __restrict__ Lpart) {
  constexpr int MT = MM / SPLITS_;
  constexpr int ITERS = MT / 64;
  const int lin = blockIdx.x;
  const int split = lin & (SPLITS_ - 1);
  const int n0 = (lin >> LOG2S_) * 64;
  const int m_begin = split * MT;

  const int tid = threadIdx.x;
  const int lane = tid & 63;
  const int wave = tid >> 6;
  const int lr = lane & 15;
  const int quad = lane >> 4;

  // sKV: K phase rows stride 520 us (1040B: DMA row + 16B pad -> frag-read banks
  // spread); VT phase rows stride 64 us with chunk^=(row&7) swizzle via DMA src.
  __shared__ __align__(16) unsigned short sKV[33280];      // 66,560 B
  __shared__ __align__(16) unsigned short sP[64 * 64];     //  8,192 B
  __shared__ float sAlpha[64];                             //    256 B
  __shared__ int sNeed;                                    // rescale flag

  if (tid == 0) sNeed = 0;  // ordered before first read by the iter-0 barriers

  // resident Q fragments: wave's 16 rows x 512 k (64 VGPRs), pre-scaled by SCALE2
  short8 qf[16];
  {
    const unsigned short* qptr = Qb + (size_t)(n0 + wave * 16 + lr) * DD + quad * 8;
#pragma unroll
    for (int ks = 0; ks < 16; ++ks) qf[ks] = ld_s8(qptr + ks * 32);
  }

  // VT DMA per-lane source geometry (swizzle in source, dest lane-contiguous):
  // group g = wave*16+j covers VT rows 8g..8g+7 -> LDS us [g*512, g*512+512).
  // lane i: LDS row r = 8g + (i>>3), chunk c' = i&7; source chunk c = c' ^ (r&7).
  const int vrb = lane >> 3;                                   // 0..7
  const int vcb = ((lane & 7) ^ vrb) * 8;                      // r&7 == vrb
  const unsigned short* vsrc0 = VTb + (size_t)(wave * 128 + vrb) * MM + vcb;
  unsigned short* vdst0 = &sKV[wave * 16 * 512];

  floatx4 o[32];  // [rt*8+ct] : O rows rt*16+quad*4+reg, col wave*128+ct*16+lr
#pragma unroll
  for (int i = 0; i < 32; ++i) o[i] = {0.f, 0.f, 0.f, 0.f};
  float mrow[4] = {NEG_INF, NEG_INF, NEG_INF, NEG_INF};
  float lrow[4] = {0.f, 0.f, 0.f, 0.f};

  for (int it = 0; it < ITERS; ++it) {
    const int m0 = m_begin + it * 64;

    // ---- stage K tile: one DMA per row (64 lanes x 16B = exactly 1024B row)
#pragma unroll
    for (int i = 0; i < 16; ++i) {
      const int r = wave * 16 + i;  // wave-uniform LDS dest
      async_lds16(Kb + (size_t)(m0 + r) * DD + lane * 8, &sKV[r * 520]);
    }
    __syncthreads();  // drains vmcnt -> K visible

    // ---- S = Q K^T (wave: its 16 rows x 64 cols), logits already in log2 units
    floatx4 s[4];
#pragma unroll
    for (int ct = 0; ct < 4; ++ct) s[ct] = {0.f, 0.f, 0.f, 0.f};
    __builtin_amdgcn_s_setprio(1);
#pragma unroll
    for (int ks = 0; ks < 16; ++ks) {
      const unsigned short* kb = &sKV[ks * 32 + quad * 8];
#pragma unroll
      for (int ct = 0; ct < 4; ++ct) {
        short8 b = ld_s8(kb + (ct * 16 + lr) * 520);
        s[ct] = __builtin_amdgcn_mfma_f32_16x16x32_bf16(qf[ks], b, s[ct], 0, 0, 0);
      }
    }
    __builtin_amdgcn_s_setprio(0);
    __syncthreads();  // all waves done with K region

    // ---- stage VT tile via DMA (swizzled source); latency hidden by softmax
    {
      const unsigned short* src = vsrc0 + m0;
#pragma unroll
      for (int j = 0; j < 16; ++j)
        async_lds16(src + (size_t)j * 8 * MM, vdst0 + j * 512);
    }

    // ---- online softmax with deferred max (T13), DPP rotate-reduce (VALU).
    float alpha[4];
    bool anyresc = false;
#pragma unroll
    for (int r = 0; r < 4; ++r) {
      float mx = fmaxf(fmaxf(s[0][r], s[1][r]), fmaxf(s[2][r], s[3][r]));
      mx = row_max16(mx);
      float mnew = (mx > mrow[r] + DEFER_THR) ? mx : mrow[r];  // -inf: always take
      alpha[r] = EXP2F(mrow[r] - mnew);  // 1 when deferred; 0 on first iter
      anyresc = anyresc || (mnew != mrow[r]);
      mrow[r] = mnew;
      float rs = 0.f;
#pragma unroll
      for (int ct = 0; ct < 4; ++ct) {
        float p = EXP2F(s[ct][r] - mnew);   // bounded by 2^THR
        s[ct][r] = p;
        rs += p;
      }
      rs = row_sum16(rs);
      lrow[r] = lrow[r] * alpha[r] + rs;
    }
    if (__any(anyresc)) {
      if (lane == 0) sNeed = 1;   // benign multi-wave race: all write 1
    }
    if (lr == 0) {
#pragma unroll
      for (int r = 0; r < 4; ++r) sAlpha[wave * 16 + quad * 4 + r] = alpha[r];
    }

    // ---- P (C layout) -> shared LDS bf16, stride 64 us, chunk-XOR swizzle.
#pragma unroll
    for (int ct = 0; ct < 4; ++ct)
#pragma unroll
      for (int r = 0; r < 4; ++r)
        sP[(wave * 16 + quad * 4 + r) * 64 +
           (((2 * ct + (lr >> 3)) ^ (2 * quad)) * 8) + (lr & 7)] = f2bf(s[ct][r]);

    __syncthreads();  // drains VT DMA; P + alphas + flag visible

    // ---- rescale O by all-row alphas -- only when some row actually rescaled
    if (sNeed) {      // block-uniform branch; ~never taken after iter 0
      floatx4 af[4];
#pragma unroll
      for (int rt = 0; rt < 4; ++rt) {
        float4 t = ld_f4(&sAlpha[rt * 16 + quad * 4]);
        af[rt] = {t.x, t.y, t.z, t.w};
      }
#pragma unroll
      for (int rt = 0; rt < 4; ++rt)
#pragma unroll
        for (int ct = 0; ct < 8; ++ct)
#pragma unroll
          for (int r = 0; r < 4; ++r) o[rt * 8 + ct][r] *= af[rt][r];
    }

    // ---- O += P V (D-split): A = P rows (all 64), B = V[m][dcol], wave's 128 d-cols
    __builtin_amdgcn_s_setprio(1);
#pragma unroll
    for (int ks = 0; ks < 2; ++ks) {
      short8 pa[4];
#pragma unroll
      for (int rt = 0; rt < 4; ++rt)
        pa[rt] = ld_s8(&sP[(rt * 16 + lr) * 64 +
                           (((4 * ks + quad) ^ (2 * ((lr >> 2) & 3))) * 8)]);
#pragma unroll
      for (int ct = 0; ct < 8; ++ct) {
        const int r = wave * 128 + ct * 16 + lr;  // VT LDS row = d-col; r&7 == lr&7
        short8 b = ld_s8(&sKV[r * 64 + (((ks * 4 + quad) ^ (lr & 7)) * 8)]);
#pragma unroll
        for (int rt = 0; rt < 4; ++rt)
          o[rt * 8 + ct] = __builtin_amdgcn_mfma_f32_16x16x32_bf16(pa[rt], b,
                                                                   o[rt * 8 + ct], 0, 0, 0);
      }
    }
    __builtin_amdgcn_s_setprio(0);
    __syncthreads();  // sKV/sP/sAlpha free for next iter's DMA
    if (tid == 0) sNeed = 0;  // all reads done (pre-barrier); next set after B1
  }

  // ---- epilogue: unnormalized partials (D-split layout)
  unsigned short* op = Opart + (size_t)split * NN * DD;
#pragma unroll
  for (int rt = 0; rt < 4; ++rt)
#pragma unroll
    for (int ct = 0; ct < 8; ++ct) {
      int row = n0 + rt * 16 + quad * 4;
      int col = wave * 128 + ct * 16 + lr;
#pragma unroll
      for (int r = 0; r < 4; ++r)
        op[(size_t)(row + r) * DD + col] = f2bf(o[rt * 8 + ct][r]);
    }
  const int grow = n0 + wave * 16 + quad * 4;
  if (lr == 0) {
#pragma unroll
    for (int r = 0; r < 4; ++r) {
      Mpart[split * NN + grow + r] = mrow[r];
      Lpart[split * NN + grow + r] = lrow[r];
    }
  }
}

// ---------------------------------------------------------------------------
// Kernel 3: exact softmax merge of SPLITS partials. 8 elems/thread, b128 I/O.
// grid (N*D/2048), block 256.
// ---------------------------------------------------------------------------
template <int SPLITS_>
__global__ void combine_kernel(const unsigned short* __restrict__ Op,
                               const float* __restrict__ Mp,
                               const float* __restrict__ Lp,
                               float* __restrict__ out) {
  constexpr size_t NDv = (size_t)NN * DD;
  size_t base = ((size_t)blockIdx.x * 256 + threadIdx.x) * 8;
  int n = (int)(base >> 9);
  float mv[SPLITS_];
  float ms = NEG_INF;
#pragma unroll
  for (int s = 0; s < SPLITS_; ++s) {
    mv[s] = Mp[s * NN + n];
    ms = fmaxf(ms, mv[s]);
  }
  float num[8];
#pragma unroll
  for (int j = 0; j < 8; ++j) num[j] = 0.f;
  float den = 0.f;
#pragma unroll
  for (int s = 0; s < SPLITS_; ++s) {
    float w = EXP2F(mv[s] - ms);
    den += w * Lp[s * NN + n];
    uintx4 u = ld_u4(Op + s * NDv + base);
#pragma unroll
    for (int j = 0; j < 4; ++j) {
      num[2 * j]     += w * bf2f((unsigned short)(u[j] & 0xffffu));
      num[2 * j + 1] += w * bf2f((unsigned short)(u[j] >> 16));
    }
  }
  float inv = 1.f / den;
  float4 o0 = {num[0] * inv, num[1] * inv, num[2] * inv, num[3] * inv};
  float4 o1 = {num[4] * inv, num[5] * inv, num[6] * inv, num[7] * inv};
  __builtin_memcpy(__builtin_assume_aligned(out + base, 16), &o0, 16);
  __builtin_memcpy(__builtin_assume_aligned(out + base + 4, 16), &o1, 16);
}

// ---------------------------------------------------------------------------
extern "C" void kernel_launch(void* const* d_in, const int* in_sizes, int n_in,
                              void* d_out, int out_size, void* d_ws, size_t ws_size,
                              hipStream_t stream) {
  const float* x  = (const float*)d_in[0];
  const float* dx = (const float*)d_in[1];
  const float* Wq = (const float*)d_in[2];
  const float* bq = (const float*)d_in[3];
  const float* Wk = (const float*)d_in[4];
  const float* bk = (const float*)d_in[5];
  const float* Wv = (const float*)d_in[6];
  const float* bv = (const float*)d_in[7];
  float* out = (float*)d_out;

  const size_t ND = (size_t)NN * DD;          // 4,194,304
  const size_t WBE = (size_t)3 * DD * DD;     //   786,432
  unsigned short* Qb  = (unsigned short*)d_ws;     // bf16, ND (pre-scaled)
  unsigned short* Kb  = Qb + ND;                   // bf16, ND
  unsigned short* VTb = Kb + ND;                   // bf16, ND (transposed V)
  unsigned short* Wb  = VTb + ND;                  // bf16, 3*D*D
  unsigned short* Op  = Wb + WBE;                  // bf16, splits*ND partial O

  auto bytes_for = [&](size_t S) {
    return (3 * ND + WBE + S * ND) * 2 + S * (size_t)NN * 8;
  };
  const int splits = (ws_size >= bytes_for(4)) ? 4 : 2;  // ws_size fixed -> same every call
  float* Mp = (float*)(Op + (size_t)splits * ND);
  float* Lp = Mp + (size_t)splits * NN;

  hipLaunchKernelGGL(prep_w, dim3(DD * DD / 2048, 1, 3), dim3(256), 0, stream,
                     Wq, Wk, Wv, Wb);
  hipLaunchKernelGGL(qkv_proj, dim3(NN / 64, 2, 3), dim3(256), 0, stream,
                     x, dx, Wb, bq, bk, bv, Qb, Kb, VTb);
  if (splits == 4) {
    hipLaunchKernelGGL((flash_attn<4, 2>), dim3(NN / 64 * 4), dim3(256), 0, stream,
                       Qb, Kb, VTb, Op, Mp, Lp);
    hipLaunchKernelGGL(combine_kernel<4>, dim3((unsigned)(ND / 2048)), dim3(256), 0, stream,
                       Op, Mp, Lp, out);
  } else {
    hipLaunchKernelGGL((flash_attn<2, 1>), dim3(NN / 64 * 2), dim3(256), 0, stream,
                       Qb, Kb, VTb, Op, Mp, Lp);
    hipLaunchKernelGGL(combine_kernel<2>, dim3((unsigned)(ND / 2048)), dim3(256), 0, stream,
                       Op, Mp, Lp, out);
  }
}

// Round 8
// 296.764 us; speedup vs baseline: 1.0805x; 1.0193x over previous
//
#include <hip/hip_runtime.h>
#include <stdint.h>

// DomainAttentionLayer: out = softmax((x Wq^T + bq)(dx Wk^T + bk)^T / sqrt(D)) (dx Wv^T + bv)
// N = M = 8192, D = 512, fp32 in/out; internal compute bf16 MFMA.
//
// Pipeline:
//   0) prep_w    : W fp32 -> bf16 (once)
//   1) qkv_proj  : bf16 GEMMs, bias fused; W tile via global_load_lds DMA.
//                  R10: 3 blocks/CU (was 2) -- 768 blocks now fit one balanced
//                  dispatch round (768 = 256 CU x 3), removing the 2-round
//                  tail where half the CUs idled.
//   2) flash_attn: R7 verified (203 us steady) -- at structural LDS floor:
//                  4-wave S-split w/ register Q => 4x K-frag LDS redundancy is
//                  inherent; all alternatives violate reg/LDS budgets (R5/R8
//                  measured worse). Not edited further.
//   3) combine   : exact log-sum-exp merge of partials -> fp32 out

#define DEV __device__ __forceinline__

typedef short short8 __attribute__((ext_vector_type(8)));     // 8 bf16 (4 VGPRs) MFMA frag
typedef float floatx4 __attribute__((ext_vector_type(4)));    // MFMA accum
typedef unsigned int uintx4 __attribute__((ext_vector_type(4)));
typedef unsigned short ushortx4 __attribute__((ext_vector_type(4)));

constexpr int NN = 8192;
constexpr int MM = 8192;
constexpr int DD = 512;
constexpr float SCALE2 = 0.0637587160f;         // log2(e) / sqrt(512), folded into Q
constexpr float DEFER_THR = 6.0f;               // T13: P bounded by 2^6; exact math

#define NEG_INF (-__builtin_inff())

#if defined(__has_builtin)
#if __has_builtin(__builtin_amdgcn_exp2f)
#define EXP2F(x) __builtin_amdgcn_exp2f(x)
#else
#define EXP2F(x) exp2f(x)
#endif
#else
#define EXP2F(x) exp2f(x)
#endif

DEV unsigned short f2bf(float f) {              // RNE fp32 -> bf16 bits
  unsigned u = __builtin_bit_cast(unsigned, f);
  return (unsigned short)((u + 0x7FFFu + ((u >> 16) & 1u)) >> 16);
}
DEV float bf2f(unsigned short h) {
  unsigned u = ((unsigned)h) << 16;
  return __builtin_bit_cast(float, u);
}

// DPP rotate within 16-lane row (VALU pipe; row_ror:N = 0x120+N)
template <int CTRL>
DEV float dpp_rot(float x) {
  int xi = __builtin_bit_cast(int, x);
  return __builtin_bit_cast(float,
      __builtin_amdgcn_update_dpp(xi, xi, CTRL, 0xf, 0xf, false));
}
DEV float row_max16(float x) {   // max over the lane's 16-lane DPP row
  x = fmaxf(x, dpp_rot<0x121>(x));   // ror:1
  x = fmaxf(x, dpp_rot<0x122>(x));   // ror:2
  x = fmaxf(x, dpp_rot<0x124>(x));   // ror:4
  x = fmaxf(x, dpp_rot<0x128>(x));   // ror:8
  return x;
}
DEV float row_sum16(float x) {   // sum over the lane's 16-lane DPP row
  x += dpp_rot<0x121>(x);
  x += dpp_rot<0x122>(x);
  x += dpp_rot<0x124>(x);
  x += dpp_rot<0x128>(x);
  return x;
}

// TBAA-safe vector ld/st (memcpy compiles to single b128/b64 with assumed alignment)
DEV short8 ld_s8(const void* p) {
  short8 v; __builtin_memcpy(&v, __builtin_assume_aligned(p, 16), 16); return v;
}
DEV uintx4 ld_u4(const void* p) {
  uintx4 v; __builtin_memcpy(&v, __builtin_assume_aligned(p, 16), 16); return v;
}
DEV void st_u4(void* p, uintx4 v) {
  __builtin_memcpy(__builtin_assume_aligned(p, 16), &v, 16);
}
DEV void st_us4(void* p, ushortx4 v) {
  __builtin_memcpy(__builtin_assume_aligned(p, 8), &v, 8);
}
DEV float4 ld_f4(const void* p) {
  float4 v; __builtin_memcpy(&v, __builtin_assume_aligned(p, 16), 16); return v;
}

DEV void async_lds16(const void* g, const void* l) {  // global -> LDS DMA, 16B/lane
  __builtin_amdgcn_global_load_lds(
      (const __attribute__((address_space(1))) unsigned int*)g,
      (__attribute__((address_space(3))) unsigned int*)l, 16, 0, 0);
}

// ---------------------------------------------------------------------------
// Kernel 0: W fp32 -> bf16, once. grid (128, 1, 3), block 256, 8 elems/thread.
// ---------------------------------------------------------------------------
__global__ void prep_w(const float* __restrict__ Wq, const float* __restrict__ Wk,
                       const float* __restrict__ Wv, unsigned short* __restrict__ Wb) {
  const int z = blockIdx.z;
  const float* src = (z == 0) ? Wq : (z == 1) ? Wk : Wv;
  unsigned short* dst = Wb + (size_t)z * DD * DD;
  size_t idx = ((size_t)blockIdx.x * 256 + threadIdx.x) * 8;
  float4 a = ld_f4(src + idx);
  float4 b = ld_f4(src + idx + 4);
  ushortx4 lo = {f2bf(a.x), f2bf(a.y), f2bf(a.z), f2bf(a.w)};
  ushortx4 hi = {f2bf(b.x), f2bf(b.y), f2bf(b.z), f2bf(b.w)};
  st_us4(dst + idx, lo);
  st_us4(dst + idx + 4, hi);
}

// ---------------------------------------------------------------------------
// Kernel 1: QKV projection. grid (128, 2, 3), block 256, 3 blocks/CU (R10).
// Tile 64 rows x 256 cols, BK=64. W tile staged by global_load_lds DMA --
// swizzle (chunk ^= row&7) folded into per-lane SOURCE addresses, dest
// lane-contiguous. A tile manual (fp32->bf16 convert) hides the DMA latency.
// z=0: Q (scaled by SCALE2) -> Qb[N][D]; z=1: K -> Kb[M][D]; z=2: V -> VTb[D][M].
// LDS 40 KB/block: 3 x 40 = 120 <= 160 KB; regs ~130 <= 170 (512/3) -> 3/CU.
// ---------------------------------------------------------------------------
__global__ __launch_bounds__(256, 3)
void qkv_proj(const float* __restrict__ x, const float* __restrict__ dx,
              const unsigned short* __restrict__ Wb,
              const float* __restrict__ bq, const float* __restrict__ bk,
              const float* __restrict__ bv,
              unsigned short* __restrict__ Qb, unsigned short* __restrict__ Kb,
              unsigned short* __restrict__ VTb) {
  const int z = blockIdx.z;
  const float* A = (z == 0) ? x : dx;
  const unsigned short* W = Wb + (size_t)z * DD * DD;
  const float* bias = (z == 0) ? bq : (z == 1) ? bk : bv;

  const int r0 = blockIdx.x * 64;
  const int c0 = blockIdx.y * 256;
  const int tid = threadIdx.x;
  const int lane = tid & 63;
  const int wave = tid >> 6;
  const int lr = lane & 15;
  const int quad = lane >> 4;

  __shared__ __align__(16) unsigned short As[64 * 64];   //  8 KB
  __shared__ __align__(16) unsigned short Ws[256 * 64];  // 32 KB

  // W DMA per-lane source geometry (same pattern as flash VT staging):
  // group g covers W rows 8g..8g+7 -> Ws us [g*512, g*512+512).
  // lane i: row r = 8g+(i>>3), dest chunk c' = i&7, source chunk c = c'^(r&7).
  const int vrb = lane >> 3;                       // 0..7
  const int vcb = ((lane & 7) ^ vrb) * 8;          // us offset of source chunk

  floatx4 o[16];
#pragma unroll
  for (int i = 0; i < 16; ++i) o[i] = {0.f, 0.f, 0.f, 0.f};

  for (int k0 = 0; k0 < DD; k0 += 64) {
    // issue W tile DMA: 32 groups of 8 rows; wave w takes groups w*8..w*8+7
#pragma unroll
    for (int j = 0; j < 8; ++j) {
      const int g = wave * 8 + j;
      async_lds16(W + (size_t)(c0 + g * 8 + vrb) * DD + k0 + vcb, &Ws[g * 512]);
    }
    // stage A tile (fp32 -> bf16): 64 rows x 64 k, 4 float4 per thread
#pragma unroll
    for (int i = 0; i < 4; ++i) {
      int idx = i * 256 + tid;
      int r = idx >> 4, c4 = idx & 15;
      float4 v = ld_f4(A + (size_t)(r0 + r) * DD + k0 + c4 * 4);
      ushortx4 pk = {f2bf(v.x), f2bf(v.y), f2bf(v.z), f2bf(v.w)};
      st_us4(&As[r * 64 + (((c4 >> 1) ^ (r & 7)) * 8) + (c4 & 1) * 4], pk);
    }
    __syncthreads();  // drains W DMA (vmcnt) + A writes

    short8 a[2];
#pragma unroll
    for (int ks = 0; ks < 2; ++ks)
      a[ks] = ld_s8(&As[(wave * 16 + lr) * 64 + (((ks * 4 + quad) ^ (lr & 7)) * 8)]);
#pragma unroll
    for (int ct = 0; ct < 16; ++ct) {
#pragma unroll
      for (int ks = 0; ks < 2; ++ks) {
        short8 b = ld_s8(&Ws[(ct * 16 + lr) * 64 + (((ks * 4 + quad) ^ (lr & 7)) * 8)]);
        o[ct] = __builtin_amdgcn_mfma_f32_16x16x32_bf16(a[ks], b, o[ct], 0, 0, 0);
      }
    }
    __syncthreads();
  }

  // epilogue: bias (+Q scale), store. C layout: col = lr, row = quad*4 + reg.
#pragma unroll
  for (int ct = 0; ct < 16; ++ct) {
    int col = c0 + ct * 16 + lr;
    float bv_ = bias[col];
    int rowb = r0 + wave * 16 + quad * 4;
    if (z == 2) {  // VT[col][row], 4 consecutive rows -> 8B store
      ushortx4 pk = {f2bf(o[ct][0] + bv_), f2bf(o[ct][1] + bv_),
                     f2bf(o[ct][2] + bv_), f2bf(o[ct][3] + bv_)};
      st_us4(VTb + (size_t)col * MM + rowb, pk);
    } else {
      unsigned short* Outp = (z == 0) ? Qb : Kb;
      float sc = (z == 0) ? SCALE2 : 1.f;
#pragma unroll
      for (int r = 0; r < 4; ++r)
        Outp[(size_t)(rowb + r) * DD + col] = f2bf((o[ct][r] + bv_) * sc);
    }
  }
}

// ---------------------------------------------------------------------------
// Kernel 2: flash attention (R7 verified, ~203 us). 1-D grid (N/64 * SPLITS_),
// block 256, 2 blocks/CU. S phase: wave w owns q-rows [16w,16w+16). PV phase
// (D-split): wave w computes O[all 64 rows][cols 128w..128w+128); P (64x64) +
// alphas shared via LDS. T13 defer-max; T5 setprio; DPP rotate-reduce softmax.
// sP: stride 64 us, 16B-chunk swizzled: chunk' = chunk ^ (2*((row>>2)&3)).
// LDS 75,016 B -> 2 blocks/CU, no spill. At structural LDS floor -- frozen.
// ---------------------------------------------------------------------------
template <int SPLITS_, int LOG2S_>
__global__ __launch_bounds__(256, 2)
void flash_attn(const unsigned short* __restrict__ Qb,
                const unsigned short* __restrict__ Kb,
                const unsigned short* __restrict__ VTb,
                unsigned short* __restrict__ Opart,
                float* __restrict__ Mpart, float* __restrict__ Lpart) {
  constexpr int MT = MM / SPLITS_;
  constexpr int ITERS = MT / 64;
  const int lin = blockIdx.x;
  const int split = lin & (SPLITS_ - 1);
  const int n0 = (lin >> LOG2S_) * 64;
  const int m_begin = split * MT;

  const int tid = threadIdx.x;
  const int lane = tid & 63;
  const int wave = tid >> 6;
  const int lr = lane & 15;
  const int quad = lane >> 4;

  // sKV: K phase rows stride 520 us (1040B: DMA row + 16B pad -> frag-read banks
  // spread); VT phase rows stride 64 us with chunk^=(row&7) swizzle via DMA src.
  __shared__ __align__(16) unsigned short sKV[33280];      // 66,560 B
  __shared__ __align__(16) unsigned short sP[64 * 64];     //  8,192 B
  __shared__ float sAlpha[64];                             //    256 B
  __shared__ int sNeed;                                    // rescale flag

  if (tid == 0) sNeed = 0;  // ordered before first read by the iter-0 barriers

  // resident Q fragments: wave's 16 rows x 512 k (64 VGPRs), pre-scaled by SCALE2
  short8 qf[16];
  {
    const unsigned short* qptr = Qb + (size_t)(n0 + wave * 16 + lr) * DD + quad * 8;
#pragma unroll
    for (int ks = 0; ks < 16; ++ks) qf[ks] = ld_s8(qptr + ks * 32);
  }

  // VT DMA per-lane source geometry (swizzle in source, dest lane-contiguous):
  // group g = wave*16+j covers VT rows 8g..8g+7 -> LDS us [g*512, g*512+512).
  // lane i: LDS row r = 8g + (i>>3), chunk c' = i&7; source chunk c = c' ^ (r&7).
  const int vrb = lane >> 3;                                   // 0..7
  const int vcb = ((lane & 7) ^ vrb) * 8;                      // r&7 == vrb
  const unsigned short* vsrc0 = VTb + (size_t)(wave * 128 + vrb) * MM + vcb;
  unsigned short* vdst0 = &sKV[wave * 16 * 512];

  floatx4 o[32];  // [rt*8+ct] : O rows rt*16+quad*4+reg, col wave*128+ct*16+lr
#pragma unroll
  for (int i = 0; i < 32; ++i) o[i] = {0.f, 0.f, 0.f, 0.f};
  float mrow[4] = {NEG_INF, NEG_INF, NEG_INF, NEG_INF};
  float lrow[4] = {0.f, 0.f, 0.f, 0.f};

  for (int it = 0; it < ITERS; ++it) {
    const int m0 = m_begin + it * 64;

    // ---- stage K tile: one DMA per row (64 lanes x 16B = exactly 1024B row)
#pragma unroll
    for (int i = 0; i < 16; ++i) {
      const int r = wave * 16 + i;  // wave-uniform LDS dest
      async_lds16(Kb + (size_t)(m0 + r) * DD + lane * 8, &sKV[r * 520]);
    }
    __syncthreads();  // drains vmcnt -> K visible

    // ---- S = Q K^T (wave: its 16 rows x 64 cols), logits already in log2 units
    floatx4 s[4];
#pragma unroll
    for (int ct = 0; ct < 4; ++ct) s[ct] = {0.f, 0.f, 0.f, 0.f};
    __builtin_amdgcn_s_setprio(1);
#pragma unroll
    for (int ks = 0; ks < 16; ++ks) {
      const unsigned short* kb = &sKV[ks * 32 + quad * 8];
#pragma unroll
      for (int ct = 0; ct < 4; ++ct) {
        short8 b = ld_s8(kb + (ct * 16 + lr) * 520);
        s[ct] = __builtin_amdgcn_mfma_f32_16x16x32_bf16(qf[ks], b, s[ct], 0, 0, 0);
      }
    }
    __builtin_amdgcn_s_setprio(0);
    __syncthreads();  // all waves done with K region

    // ---- stage VT tile via DMA (swizzled source); latency hidden by softmax
    {
      const unsigned short* src = vsrc0 + m0;
#pragma unroll
      for (int j = 0; j < 16; ++j)
        async_lds16(src + (size_t)j * 8 * MM, vdst0 + j * 512);
    }

    // ---- online softmax with deferred max (T13), DPP rotate-reduce (VALU).
    float alpha[4];
    bool anyresc = false;
#pragma unroll
    for (int r = 0; r < 4; ++r) {
      float mx = fmaxf(fmaxf(s[0][r], s[1][r]), fmaxf(s[2][r], s[3][r]));
      mx = row_max16(mx);
      float mnew = (mx > mrow[r] + DEFER_THR) ? mx : mrow[r];  // -inf: always take
      alpha[r] = EXP2F(mrow[r] - mnew);  // 1 when deferred; 0 on first iter
      anyresc = anyresc || (mnew != mrow[r]);
      mrow[r] = mnew;
      float rs = 0.f;
#pragma unroll
      for (int ct = 0; ct < 4; ++ct) {
        float p = EXP2F(s[ct][r] - mnew);   // bounded by 2^THR
        s[ct][r] = p;
        rs += p;
      }
      rs = row_sum16(rs);
      lrow[r] = lrow[r] * alpha[r] + rs;
    }
    if (__any(anyresc)) {
      if (lane == 0) sNeed = 1;   // benign multi-wave race: all write 1
    }
    if (lr == 0) {
#pragma unroll
      for (int r = 0; r < 4; ++r) sAlpha[wave * 16 + quad * 4 + r] = alpha[r];
    }

    // ---- P (C layout) -> shared LDS bf16, stride 64 us, chunk-XOR swizzle.
#pragma unroll
    for (int ct = 0; ct < 4; ++ct)
#pragma unroll
      for (int r = 0; r < 4; ++r)
        sP[(wave * 16 + quad * 4 + r) * 64 +
           (((2 * ct + (lr >> 3)) ^ (2 * quad)) * 8) + (lr & 7)] = f2bf(s[ct][r]);

    __syncthreads();  // drains VT DMA; P + alphas + flag visible

    // ---- rescale O by all-row alphas -- only when some row actually rescaled
    if (sNeed) {      // block-uniform branch; ~never taken after iter 0
      floatx4 af[4];
#pragma unroll
      for (int rt = 0; rt < 4; ++rt) {
        float4 t = ld_f4(&sAlpha[rt * 16 + quad * 4]);
        af[rt] = {t.x, t.y, t.z, t.w};
      }
#pragma unroll
      for (int rt = 0; rt < 4; ++rt)
#pragma unroll
        for (int ct = 0; ct < 8; ++ct)
#pragma unroll
          for (int r = 0; r < 4; ++r) o[rt * 8 + ct][r] *= af[rt][r];
    }

    // ---- O += P V (D-split): A = P rows (all 64), B = V[m][dcol], wave's 128 d-cols
    __builtin_amdgcn_s_setprio(1);
#pragma unroll
    for (int ks = 0; ks < 2; ++ks) {
      short8 pa[4];
#pragma unroll
      for (int rt = 0; rt < 4; ++rt)
        pa[rt] = ld_s8(&sP[(rt * 16 + lr) * 64 +
                           (((4 * ks + quad) ^ (2 * ((lr >> 2) & 3))) * 8)]);
#pragma unroll
      for (int ct = 0; ct < 8; ++ct) {
        const int r = wave * 128 + ct * 16 + lr;  // VT LDS row = d-col; r&7 == lr&7
        short8 b = ld_s8(&sKV[r * 64 + (((ks * 4 + quad) ^ (lr & 7)) * 8)]);
#pragma unroll
        for (int rt = 0; rt < 4; ++rt)
          o[rt * 8 + ct] = __builtin_amdgcn_mfma_f32_16x16x32_bf16(pa[rt], b,
                                                                   o[rt * 8 + ct], 0, 0, 0);
      }
    }
    __builtin_amdgcn_s_setprio(0);
    __syncthreads();  // sKV/sP/sAlpha free for next iter's DMA
    if (tid == 0) sNeed = 0;  // all reads done (pre-barrier); next set after B1
  }

  // ---- epilogue: unnormalized partials (D-split layout)
  unsigned short* op = Opart + (size_t)split * NN * DD;
#pragma unroll
  for (int rt = 0; rt < 4; ++rt)
#pragma unroll
    for (int ct = 0; ct < 8; ++ct) {
      int row = n0 + rt * 16 + quad * 4;
      int col = wave * 128 + ct * 16 + lr;
#pragma unroll
      for (int r = 0; r < 4; ++r)
        op[(size_t)(row + r) * DD + col] = f2bf(o[rt * 8 + ct][r]);
    }
  const int grow = n0 + wave * 16 + quad * 4;
  if (lr == 0) {
#pragma unroll
    for (int r = 0; r < 4; ++r) {
      Mpart[split * NN + grow + r] = mrow[r];
      Lpart[split * NN + grow + r] = lrow[r];
    }
  }
}

// ---------------------------------------------------------------------------
// Kernel 3: exact softmax merge of SPLITS partials. 8 elems/thread, b128 I/O.
// grid (N*D/2048), block 256.
// ---------------------------------------------------------------------------
template <int SPLITS_>
__global__ void combine_kernel(const unsigned short* __restrict__ Op,
                               const float* __restrict__ Mp,
                               const float* __restrict__ Lp,
                               float* __restrict__ out) {
  constexpr size_t NDv = (size_t)NN * DD;
  size_t base = ((size_t)blockIdx.x * 256 + threadIdx.x) * 8;
  int n = (int)(base >> 9);
  float mv[SPLITS_];
  float ms = NEG_INF;
#pragma unroll
  for (int s = 0; s < SPLITS_; ++s) {
    mv[s] = Mp[s * NN + n];
    ms = fmaxf(ms, mv[s]);
  }
  float num[8];
#pragma unroll
  for (int j = 0; j < 8; ++j) num[j] = 0.f;
  float den = 0.f;
#pragma unroll
  for (int s = 0; s < SPLITS_; ++s) {
    float w = EXP2F(mv[s] - ms);
    den += w * Lp[s * NN + n];
    uintx4 u = ld_u4(Op + s * NDv + base);
#pragma unroll
    for (int j = 0; j < 4; ++j) {
      num[2 * j]     += w * bf2f((unsigned short)(u[j] & 0xffffu));
      num[2 * j + 1] += w * bf2f((unsigned short)(u[j] >> 16));
    }
  }
  float inv = 1.f / den;
  float4 o0 = {num[0] * inv, num[1] * inv, num[2] * inv, num[3] * inv};
  float4 o1 = {num[4] * inv, num[5] * inv, num[6] * inv, num[7] * inv};
  __builtin_memcpy(__builtin_assume_aligned(out + base, 16), &o0, 16);
  __builtin_memcpy(__builtin_assume_aligned(out + base + 4, 16), &o1, 16);
}

// ---------------------------------------------------------------------------
extern "C" void kernel_launch(void* const* d_in, const int* in_sizes, int n_in,
                              void* d_out, int out_size, void* d_ws, size_t ws_size,
                              hipStream_t stream) {
  const float* x  = (const float*)d_in[0];
  const float* dx = (const float*)d_in[1];
  const float* Wq = (const float*)d_in[2];
  const float* bq = (const float*)d_in[3];
  const float* Wk = (const float*)d_in[4];
  const float* bk = (const float*)d_in[5];
  const float* Wv = (const float*)d_in[6];
  const float* bv = (const float*)d_in[7];
  float* out = (float*)d_out;

  const size_t ND = (size_t)NN * DD;          // 4,194,304
  const size_t WBE = (size_t)3 * DD * DD;     //   786,432
  unsigned short* Qb  = (unsigned short*)d_ws;     // bf16, ND (pre-scaled)
  unsigned short* Kb  = Qb + ND;                   // bf16, ND
  unsigned short* VTb = Kb + ND;                   // bf16, ND (transposed V)
  unsigned short* Wb  = VTb + ND;                  // bf16, 3*D*D
  unsigned short* Op  = Wb + WBE;                  // bf16, splits*ND partial O

  auto bytes_for = [&](size_t S) {
    return (3 * ND + WBE + S * ND) * 2 + S * (size_t)NN * 8;
  };
  const int splits = (ws_size >= bytes_for(4)) ? 4 : 2;  // ws_size fixed -> same every call
  float* Mp = (float*)(Op + (size_t)splits * ND);
  float* Lp = Mp + (size_t)splits * NN;

  hipLaunchKernelGGL(prep_w, dim3(DD * DD / 2048, 1, 3), dim3(256), 0, stream,
                     Wq, Wk, Wv, Wb);
  hipLaunchKernelGGL(qkv_proj, dim3(NN / 64, 2, 3), dim3(256), 0, stream,
                     x, dx, Wb, bq, bk, bv, Qb, Kb, VTb);
  if (splits == 4) {
    hipLaunchKernelGGL((flash_attn<4, 2>), dim3(NN / 64 * 4), dim3(256), 0, stream,
                       Qb, Kb, VTb, Op, Mp, Lp);
    hipLaunchKernelGGL(combine_kernel<4>, dim3((unsigned)(ND / 2048)), dim3(256), 0, stream,
                       Op, Mp, Lp, out);
  } else {
    hipLaunchKernelGGL((flash_attn<2, 1>), dim3(NN / 64 * 2), dim3(256), 0, stream,
                       Qb, Kb, VTb, Op, Mp, Lp);
    hipLaunchKernelGGL(combine_kernel<2>, dim3((unsigned)(ND / 2048)), dim3(256), 0, stream,
                       Op, Mp, Lp, out);
  }
}